// Round 16
// baseline (280.256 us; speedup 1.0000x reference)
//
#include <hip/hip_runtime.h>

typedef __attribute__((ext_vector_type(4))) float f4;
typedef __attribute__((ext_vector_type(8))) short bfx8;
typedef __attribute__((ext_vector_type(4))) float f32x4;
typedef __attribute__((ext_vector_type(4))) unsigned int u32x4;
typedef __attribute__((ext_vector_type(4))) unsigned short u16x4;
typedef __attribute__((ext_vector_type(8))) unsigned short u16x8;
typedef unsigned short ushort_t;

#define DM 768
#define DINNER 1536
#define NH 24
#define XBCW 1664
#define DINPROJ 3224
#define NPAD1 3328
#define NCHUNK 64
#define BROWS 8192
#define PADB 72  // bf16 LDS row stride for 64-wide tiles

__device__ inline ushort_t f2bf(float f) {
    unsigned u = __builtin_bit_cast(unsigned, f);
    unsigned r = (u + 0x7FFF + ((u >> 16) & 1)) >> 16;
    return (ushort_t)r;
}
__device__ inline float bf2f(ushort_t u) {
    return __builtin_bit_cast(float, (unsigned)u << 16);
}
// direct global->LDS 16B staging. dst wave-uniform; HW adds lane*16.
__device__ inline void gl16(const void* g, void* l) {
    __builtin_amdgcn_global_load_lds((const __attribute__((address_space(1))) void*)g,
                                     (__attribute__((address_space(3))) void*)l, 16, 0, 0);
}

__global__ __launch_bounds__(256) void fill_kernel(float* out, int n, float v) {
    int i = blockIdx.x * 256 + threadIdx.x;
    if (i < n) out[i] = v;
}

// ---- f32 -> bf16 bulk convert ----
__global__ __launch_bounds__(256) void cvt_kernel(const float* __restrict__ in,
                                                  ushort_t* __restrict__ outp, long n4) {
    long i = (long)blockIdx.x * 256 + threadIdx.x;
    if (i >= n4) return;
    f4 v = *(const f4*)&in[i * 4];
    u16x4 o;
    o[0] = f2bf(v[0]); o[1] = f2bf(v[1]); o[2] = f2bf(v[2]); o[3] = f2bf(v[3]);
    *(u16x4*)&outp[i * 4] = o;
}

// ---- W_in f32 [3224][768] -> bf16 [3328][768], zero-padded rows ----
__global__ __launch_bounds__(256) void cvt_pad_kernel(const float* __restrict__ in,
                                                      ushort_t* __restrict__ outp) {
    long q = (long)blockIdx.x * 256 + threadIdx.x;
    if (q >= (long)NPAD1 * 192) return;
    int row = (int)(q / 192);
    int cq = (int)(q % 192);
    u16x4 o = {0, 0, 0, 0};
    if (row < DINPROJ) {
        f4 v = *(const f4*)&in[(long)row * DM + cq * 4];
        o[0] = f2bf(v[0]); o[1] = f2bf(v[1]); o[2] = f2bf(v[2]); o[3] = f2bf(v[3]);
    }
    *(u16x4*)&outp[q * 4] = o;
}

// ---- GEMM C = A[M][K] * B[N][K]^T, bf16 in, 3-buffer 2-deep counted-vmcnt pipeline,
//      XCD-aware block swizzle (m-major chunks per XCD). Grid nwg must be %8==0.
// EPI=0: C f32 dense (out-proj). EPI=1: split epilogue (in-proj, xBC -> bf16).
template <int EPI>
__global__ __launch_bounds__(256) void gemm_bt(const ushort_t* __restrict__ A,
                                               const ushort_t* __restrict__ B,
                                               float* __restrict__ C,
                                               int K, int ldc,
                                               ushort_t* __restrict__ zbf,
                                               ushort_t* __restrict__ xbcbf,
                                               float* __restrict__ dtbT,
                                               const float* __restrict__ dt_bias) {
    __shared__ __align__(16) ushort_t As[3][128 * 32];  // 8KB each
    __shared__ __align__(16) ushort_t Bs[3][128 * 32];
    int tid = threadIdx.x;
    int lane = tid & 63;
    int w = tid >> 6;
    int wr = w >> 1, wc = w & 1;
    // XCD swizzle: consecutive ids round-robin XCDs; remap so each XCD owns a
    // contiguous m-major slab (shares A-panels in its private L2).
    int gx = gridDim.x;
    int nwg = gx * gridDim.y;
    int id = blockIdx.y * gx + blockIdx.x;
    int per = nwg >> 3;
    int id2 = (id & 7) * per + (id >> 3);
    int m0 = (id2 / gx) * 128;
    int n0 = (id2 % gx) * 128;
    int r16 = lane & 15, kg = lane >> 4;

    int row0 = tid >> 2, cof0 = (tid & 3) * 8;
    const ushort_t* a0 = &A[(long)(m0 + row0) * K + cof0];
    const ushort_t* a1 = &A[(long)(m0 + row0 + 64) * K + cof0];
    const ushort_t* b0 = &B[(long)(n0 + row0) * K + cof0];
    const ushort_t* b1 = &B[(long)(n0 + row0 + 64) * K + cof0];
    char* asb[3] = {(char*)&As[0][0] + w * 1024, (char*)&As[1][0] + w * 1024,
                    (char*)&As[2][0] + w * 1024};
    char* bsb[3] = {(char*)&Bs[0][0] + w * 1024, (char*)&Bs[1][0] + w * 1024,
                    (char*)&Bs[2][0] + w * 1024};

    f32x4 acc[4][4] = {};
    int nk = K >> 5;

    auto issue = [&](int t) {
        int k = t << 5;
        int bi = t % 3;
        gl16(a0 + k, asb[bi]); gl16(a1 + k, asb[bi] + 4096);
        gl16(b0 + k, bsb[bi]); gl16(b1 + k, bsb[bi] + 4096);
    };
    issue(0);
    issue(1);

    for (int t = 0; t < nk; ++t) {
        if (t + 1 < nk) {  // tile t+1's 4 loads may stay in flight
            asm volatile("s_waitcnt vmcnt(4)" ::: "memory");
        } else {
            asm volatile("s_waitcnt vmcnt(0)" ::: "memory");
        }
        __builtin_amdgcn_s_barrier();   // tile t visible to all; compute(t-1) reads done
        __builtin_amdgcn_sched_barrier(0);
        if (t + 2 < nk) issue(t + 2);   // overwrites buf((t-1)%3) — safe after barrier
        const ushort_t* Asc = &As[t % 3][0];
        const ushort_t* Bsc = &Bs[t % 3][0];
        bfx8 af[4], bfr[4];
#pragma unroll
        for (int i = 0; i < 4; ++i) {
            af[i] = *(const bfx8*)&Asc[(wr * 64 + i * 16 + r16) * 32 + kg * 8];
            bfr[i] = *(const bfx8*)&Bsc[(wc * 64 + i * 16 + r16) * 32 + kg * 8];
        }
#pragma unroll
        for (int i = 0; i < 4; ++i)
#pragma unroll
            for (int j = 0; j < 4; ++j)
                acc[i][j] = __builtin_amdgcn_mfma_f32_16x16x32_bf16(af[i], bfr[j], acc[i][j], 0, 0, 0);
    }

#pragma unroll
    for (int i = 0; i < 4; ++i) {
        int rowb = m0 + wr * 64 + i * 16 + kg * 4;
#pragma unroll
        for (int j = 0; j < 4; ++j) {
            int col = n0 + wc * 64 + j * 16 + r16;
            if (EPI == 0) {
#pragma unroll
                for (int q = 0; q < 4; ++q)
                    C[(long)(rowb + q) * ldc + col] = acc[i][j][q];
            } else {
                if (n0 < DINNER) {  // z -> bf16
#pragma unroll
                    for (int q = 0; q < 4; ++q)
                        zbf[(long)(rowb + q) * DINNER + col] = f2bf(acc[i][j][q]);
                } else if (n0 < 3200) {  // xBC raw -> bf16
#pragma unroll
                    for (int q = 0; q < 4; ++q)
                        xbcbf[(long)(rowb + q) * XBCW + col - DINNER] = f2bf(acc[i][j][q]);
                } else if (col < DINPROJ) {  // dt -> softplus -> transposed
                    int h = col - 3200;
                    float bias = dt_bias[h];
#pragma unroll
                    for (int q = 0; q < 4; ++q) {
                        float v = acc[i][j][q] + bias;
                        float d = (v > 20.f) ? v : log1pf(__expf(v));
                        dtbT[(long)h * BROWS + rowb + q] = d;
                    }
                }
            }
        }
    }
}

// ---- depthwise causal conv(4) + bias + silu; bf16 in, bf16 out ----
__global__ __launch_bounds__(256) void conv_kernel(const ushort_t* __restrict__ xin,
                                                   const float* __restrict__ cw,
                                                   const float* __restrict__ cb,
                                                   ushort_t* __restrict__ xbc) {
    int ch = blockIdx.y * 256 + threadIdx.x;
    int row = blockIdx.x;
    if (ch >= XBCW) return;
    int b = row >> 12;
    int l = row & 4095;
    float acc = cb[ch];
#pragma unroll
    for (int k = 0; k < 4; ++k) {
        int ll = l - 3 + k;
        if (ll >= 0)
            acc += cw[ch * 4 + k] * bf2f(xin[(long)(b * 4096 + ll) * XBCW + ch]);
    }
    float s = acc / (1.f + __expf(-acc));
    xbc[(long)row * XBCW + ch] = f2bf(s);
}

// ---- transpose xbc channels [0,1600) -> xT[ch][row] (x columns + B columns) ----
__global__ __launch_bounds__(256) void xt_kernel(const ushort_t* __restrict__ xbc,
                                                 ushort_t* __restrict__ xT) {
    __shared__ ushort_t tile[64][PADB];
    int rt = blockIdx.x;  // 0..127 row tiles
    int ct = blockIdx.y;  // 0..24 ch tiles
    int t = threadIdx.x;
#pragma unroll
    for (int i = 0; i < 2; ++i) {
        int q = t + 256 * i;
        int r = q >> 3, cc = q & 7;
        *(u16x8*)&tile[r][cc * 8] =
            *(const u16x8*)&xbc[(long)(rt * 64 + r) * XBCW + ct * 64 + cc * 8];
    }
    __syncthreads();
#pragma unroll
    for (int i = 0; i < 2; ++i) {
        int q = t + 256 * i;
        int ch = q >> 3, sg = q & 7;
        u16x8 o;
#pragma unroll
        for (int k = 0; k < 8; ++k) o[k] = tile[sg * 8 + k][ch];
        *(u16x8*)&xT[(long)(ct * 64 + ch) * BROWS + rt * 64 + sg * 8] = o;
    }
}

// ---- per-chunk cumsum of A*dt via wave scan ----
__global__ __launch_bounds__(256) void acs_kernel(const float* __restrict__ dtbT,
                                                  const float* __restrict__ A_log,
                                                  float* __restrict__ acs,
                                                  float* __restrict__ Tsum) {
    int bh = blockIdx.x;
    int b = bh / NH, h = bh % NH;
    int t = threadIdx.x;
    int lane = t & 63;
    float A = -__expf(A_log[h]);
    const float* dp = &dtbT[(long)h * BROWS + b * 4096];
#pragma unroll
    for (int it = 0; it < 16; ++it) {
        int c = (t >> 6) + 4 * it;
        float v = A * dp[c * 64 + lane];
#pragma unroll
        for (int off = 1; off < 64; off <<= 1) {
            float u = __shfl_up(v, off, 64);
            if (lane >= off) v += u;
        }
        acs[((long)bh * NCHUNK + c) * 64 + lane] = v;
        if (lane == 63) Tsum[bh * NCHUNK + c] = v;
    }
}

// ---- phase A (MFMA): states[p][n] = sum_l (x*dt*decay)[l][p] * B[l][n] -> bf16 ----
// Wt/Bt staged from pre-transposed xT (row writes, no bank-conflicted scatter).
__global__ __launch_bounds__(256) void states_kernel(const ushort_t* __restrict__ xT,
                                                     const float* __restrict__ dtbT,
                                                     const float* __restrict__ acs,
                                                     const float* __restrict__ Tsum,
                                                     ushort_t* __restrict__ states) {
    int h = blockIdx.x, c = blockIdx.y, b = blockIdx.z;
    __shared__ __align__(16) ushort_t Wt[64 * PADB];
    __shared__ __align__(16) ushort_t Bt[64 * PADB];
    __shared__ float sDec[64];
    int t = threadIdx.x;
    long rowg0 = (long)b * 4096 + c * 64;
    long acsb = ((long)(b * NH + h) * NCHUNK + c) * 64;
    float T = Tsum[(b * NH + h) * NCHUNK + c];
    if (t < 64)
        sDec[t] = dtbT[(long)h * BROWS + rowg0 + t] * __expf(T - acs[acsb + t]);
    __syncthreads();
#pragma unroll
    for (int i = 0; i < 2; ++i) {
        int q = t + 256 * i;
        int p = q >> 3, sg = q & 7;
        u16x8 xv = *(const u16x8*)&xT[(long)(h * 64 + p) * BROWS + rowg0 + sg * 8];
        u16x8 wv;
#pragma unroll
        for (int j = 0; j < 8; ++j) wv[j] = f2bf(bf2f(xv[j]) * sDec[sg * 8 + j]);
        *(u16x8*)&Wt[p * PADB + sg * 8] = wv;
        *(u16x8*)&Bt[p * PADB + sg * 8] =
            *(const u16x8*)&xT[(long)(DINNER + p) * BROWS + rowg0 + sg * 8];
    }
    __syncthreads();
    int w = t >> 6, lane = t & 63;
    int r16 = lane & 15, kg = lane >> 4;
    bfx8 aw[2];
#pragma unroll
    for (int kk = 0; kk < 2; ++kk)
        aw[kk] = *(const bfx8*)&Wt[(w * 16 + r16) * PADB + kk * 32 + kg * 8];
    f32x4 acc[4] = {};
#pragma unroll
    for (int j = 0; j < 4; ++j)
#pragma unroll
        for (int kk = 0; kk < 2; ++kk) {
            bfx8 bb = *(const bfx8*)&Bt[(j * 16 + r16) * PADB + kk * 32 + kg * 8];
            acc[j] = __builtin_amdgcn_mfma_f32_16x16x32_bf16(aw[kk], bb, acc[j], 0, 0, 0);
        }
    __syncthreads();
#pragma unroll
    for (int j = 0; j < 4; ++j)
#pragma unroll
        for (int q = 0; q < 4; ++q)
            Wt[(w * 16 + kg * 4 + q) * PADB + j * 16 + r16] = f2bf(acc[j][q]);
    __syncthreads();
    long ob = ((long)(b * NH + h) * NCHUNK + c) * 4096;
#pragma unroll
    for (int i = 0; i < 2; ++i) {
        int q = t + 256 * i;
        int p = q >> 3, sg = q & 7;
        *(u16x8*)&states[ob + p * 64 + sg * 8] = *(const u16x8*)&Wt[p * PADB + sg * 8];
    }
}

// ---- sequential chunk scan ----
__global__ __launch_bounds__(256) void scan_kernel(const float* __restrict__ Tsum,
                                                   ushort_t* __restrict__ states) {
    int e = blockIdx.x * 256 + threadIdx.x;
    int h = blockIdx.y, b = blockIdx.z;
    long base = ((long)(b * NH + h)) * NCHUNK * 4096 + e;
    const float* Tp = &Tsum[(b * NH + h) * NCHUNK];
    float acc = 0.f;
    for (int c = 0; c < NCHUNK; ++c) {
        float cur = bf2f(states[base + (long)c * 4096]);
        states[base + (long)c * 4096] = f2bf(acc);
        acc = __expf(Tp[c]) * acc + cur;
    }
}

// ---- phase C (MFMA): Y = (C.B^T . Lm) @ xd + exp(acs) * (C @ Sprev^T) -> bf16 ybuf ----
__global__ __launch_bounds__(256) void yfull_kernel(const ushort_t* __restrict__ xbc,
                                                    const ushort_t* __restrict__ xT,
                                                    const float* __restrict__ dtbT,
                                                    const float* __restrict__ acs,
                                                    const ushort_t* __restrict__ sprev,
                                                    ushort_t* __restrict__ ybuf) {
    int h = blockIdx.x, c = blockIdx.y, b = blockIdx.z;
    __shared__ __align__(16) ushort_t Cb[64 * PADB];  // C[l][n]
    __shared__ __align__(16) ushort_t Bb[64 * PADB];  // B[s][n], later output tile [l][p]
    __shared__ __align__(16) ushort_t Xt[64 * PADB];  // xd^T[p][s]
    __shared__ __align__(16) ushort_t Sp[64 * PADB];  // sprev[p][n]
    __shared__ __align__(16) ushort_t Sm[64 * PADB];  // masked scores [l][s]
    __shared__ float sAcs[64], sE[64], sDt[64];
    int t = threadIdx.x;
    long rowg0 = (long)b * 4096 + c * 64;
    long acsb = ((long)(b * NH + h) * NCHUNK + c) * 64;
    long spb = ((long)(b * NH + h) * NCHUNK + c) * 4096;
    if (t < 64) {
        float a = acs[acsb + t];
        sAcs[t] = a;
        sE[t] = __expf(a);
        sDt[t] = dtbT[(long)h * BROWS + rowg0 + t];
    }
    __syncthreads();  // sDt used by staging below
#pragma unroll
    for (int i = 0; i < 2; ++i) {
        int q = t + 256 * i;
        int l = q >> 3, sg = q & 7;
        const ushort_t* rp = &xbc[(rowg0 + l) * (long)XBCW];
        *(u16x8*)&Cb[l * PADB + sg * 8] = *(const u16x8*)&rp[1600 + sg * 8];
        *(u16x8*)&Bb[l * PADB + sg * 8] = *(const u16x8*)&rp[DINNER + sg * 8];
        // Xt rows from pre-transposed x: p = l index here
        u16x8 xv = *(const u16x8*)&xT[(long)(h * 64 + l) * BROWS + rowg0 + sg * 8];
        u16x8 xo;
#pragma unroll
        for (int j = 0; j < 8; ++j) xo[j] = f2bf(bf2f(xv[j]) * sDt[sg * 8 + j]);
        *(u16x8*)&Xt[l * PADB + sg * 8] = xo;
        *(u16x8*)&Sp[l * PADB + sg * 8] = *(const u16x8*)&sprev[spb + l * 64 + sg * 8];
    }
    __syncthreads();
    int w = t >> 6, lane = t & 63;
    int r16 = lane & 15, kg = lane >> 4;
    // phase 1: S = C.B^T (rows l in [16w,16w+16))
    bfx8 ac[2];
#pragma unroll
    for (int kk = 0; kk < 2; ++kk)
        ac[kk] = *(const bfx8*)&Cb[(w * 16 + r16) * PADB + kk * 32 + kg * 8];
    f32x4 s_acc[4] = {};
#pragma unroll
    for (int j = 0; j < 4; ++j)
#pragma unroll
        for (int kk = 0; kk < 2; ++kk) {
            bfx8 bb = *(const bfx8*)&Bb[(j * 16 + r16) * PADB + kk * 32 + kg * 8];
            s_acc[j] = __builtin_amdgcn_mfma_f32_16x16x32_bf16(ac[kk], bb, s_acc[j], 0, 0, 0);
        }
    // mask + decay -> Sm (bf16)
#pragma unroll
    for (int j = 0; j < 4; ++j)
#pragma unroll
        for (int q = 0; q < 4; ++q) {
            int l = w * 16 + kg * 4 + q;
            int s = j * 16 + r16;
            float v = s_acc[j][q];
            v = (s <= l) ? v * __expf(sAcs[l] - sAcs[s]) : 0.f;
            Sm[l * PADB + s] = f2bf(v);
        }
    __syncthreads();
    // phase 2: Yd = Sm @ xd;  phase 3: Yo = C @ Sprev^T
    bfx8 as[2];
#pragma unroll
    for (int kk = 0; kk < 2; ++kk)
        as[kk] = *(const bfx8*)&Sm[(w * 16 + r16) * PADB + kk * 32 + kg * 8];
    f32x4 d_acc[4] = {}, o_acc[4] = {};
#pragma unroll
    for (int j = 0; j < 4; ++j)
#pragma unroll
        for (int kk = 0; kk < 2; ++kk) {
            bfx8 xb = *(const bfx8*)&Xt[(j * 16 + r16) * PADB + kk * 32 + kg * 8];
            d_acc[j] = __builtin_amdgcn_mfma_f32_16x16x32_bf16(as[kk], xb, d_acc[j], 0, 0, 0);
            bfx8 sb = *(const bfx8*)&Sp[(j * 16 + r16) * PADB + kk * 32 + kg * 8];
            o_acc[j] = __builtin_amdgcn_mfma_f32_16x16x32_bf16(ac[kk], sb, o_acc[j], 0, 0, 0);
        }
    // epilogue tile -> Bb (dead), then coalesced copy out
#pragma unroll
    for (int j = 0; j < 4; ++j)
#pragma unroll
        for (int q = 0; q < 4; ++q) {
            int l = w * 16 + kg * 4 + q;
            int p = j * 16 + r16;
            Bb[l * PADB + p] = f2bf(d_acc[j][q] + sE[l] * o_acc[j][q]);
        }
    __syncthreads();
#pragma unroll
    for (int i = 0; i < 2; ++i) {
        int q = t + 256 * i;
        int l = q >> 3, sg = q & 7;
        *(u16x8*)&ybuf[(rowg0 + l) * (long)DINNER + h * 64 + sg * 8] =
            *(const u16x8*)&Bb[l * PADB + sg * 8];
    }
}

// ---- gated RMS norm -> bf16 ----
__global__ __launch_bounds__(256) void norm_kernel(const ushort_t* __restrict__ ybuf,
                                                   const ushort_t* __restrict__ xbc,
                                                   const ushort_t* __restrict__ zbf,
                                                   const float* __restrict__ Dp,
                                                   const float* __restrict__ normw,
                                                   ushort_t* __restrict__ ybf) {
    int row = blockIdx.x;
    int t = threadIdx.x;
    float g[6];
    float ss = 0.f;
#pragma unroll
    for (int i = 0; i < 6; ++i) {
        int j = t + 256 * i;
        int h = j >> 6;
        float x = bf2f(xbc[(long)row * XBCW + j]);
        float yy = bf2f(ybuf[(long)row * DINNER + j]) + x * Dp[h];
        float z = bf2f(zbf[(long)row * DINNER + j]);
        float gz = z / (1.f + __expf(-z));
        float v = yy * gz;
        g[i] = v;
        ss += v * v;
    }
#pragma unroll
    for (int o = 32; o > 0; o >>= 1) ss += __shfl_xor(ss, o, 64);
    __shared__ float wsum[4];
    __shared__ float sscale;
    int w = t >> 6;
    if ((t & 63) == 0) wsum[w] = ss;
    __syncthreads();
    if (t == 0) {
        float tot = wsum[0] + wsum[1] + wsum[2] + wsum[3];
        sscale = rsqrtf(tot / (float)DINNER + 1e-5f);
    }
    __syncthreads();
    float sc = sscale;
#pragma unroll
    for (int i = 0; i < 6; ++i) {
        int j = t + 256 * i;
        ybf[(long)row * DINNER + j] = f2bf(g[i] * sc * normw[j]);
    }
}

extern "C" void kernel_launch(void* const* d_in, const int* in_sizes, int n_in,
                              void* d_out, int out_size, void* d_ws, size_t ws_size,
                              hipStream_t stream) {
    const float* u = (const float*)d_in[0];
    const float* W_in = (const float*)d_in[1];
    const float* conv_w = (const float*)d_in[2];
    const float* conv_b = (const float*)d_in[3];
    const float* dt_bias = (const float*)d_in[4];
    const float* A_log = (const float*)d_in[5];
    const float* Dp = (const float*)d_in[6];
    const float* norm_w = (const float*)d_in[7];
    const float* W_out = (const float*)d_in[8];
    float* out = (float*)d_out;

    char* ws = (char*)d_ws;
    size_t off = 0;
    auto alloc = [&](size_t bytes) {
        void* p = ws + off;
        off += (bytes + 255) & ~(size_t)255;
        return p;
    };
    ushort_t* zbf = (ushort_t*)alloc((size_t)BROWS * DINNER * 2);      // 25.2 MB
    ushort_t* xbcrawbf = (ushort_t*)alloc((size_t)BROWS * XBCW * 2);   // 27.3 MB (bf16, from gemm1)
    ushort_t* xbc = (ushort_t*)alloc((size_t)BROWS * XBCW * 2);        // 27.3 MB (bf16, from conv)
    ushort_t* xT = (ushort_t*)alloc((size_t)1600 * BROWS * 2);         // 26.2 MB (x+B transposed)
    float* dtbT = (float*)alloc((size_t)NH * BROWS * 4);               // 0.79 MB
    float* acs = (float*)alloc((size_t)2 * NH * NCHUNK * 64 * 4);      // 0.79 MB
    float* Tsum = (float*)alloc((size_t)2 * NH * NCHUNK * 4);          // 12 KB
    ushort_t* states = (ushort_t*)alloc((size_t)2 * NH * NCHUNK * 4096 * 2);  // 25.2 MB
    ushort_t* ybuf = (ushort_t*)alloc((size_t)BROWS * DINNER * 2);     // 25.2 MB
    // aliases with disjoint lifetimes:
    ushort_t* ybf = xbcrawbf;             // xbcrawbf dead after conv; 25.2MB <= 27.3MB
    ushort_t* ubf = ybuf;                 // u-bf16 dead after gemm1; ybuf written in yfull
    ushort_t* winbf = states;             // W_in-bf16 dead after gemm1; states written after
    ushort_t* woutbf = states;            // W_out-bf16 written after yfull consumed states

    if (off > ws_size) {
        fill_kernel<<<(out_size + 255) / 256, 256, 0, stream>>>(out, out_size, 12345.0f);
        return;
    }

    // pre-convert inputs to bf16
    cvt_kernel<<<(BROWS * DM / 4 + 255) / 256, 256, 0, stream>>>(u, ubf, (long)BROWS * DM / 4);
    cvt_pad_kernel<<<((long)NPAD1 * 192 + 255) / 256, 256, 0, stream>>>(W_in, winbf);

    // in-projection with split epilogue (z bf16 / xBC bf16 / dt softplus transposed)
    gemm_bt<1><<<dim3(26, 64), 256, 0, stream>>>(ubf, winbf, nullptr, DM, 0,
                                                 zbf, xbcrawbf, dtbT, dt_bias);

    conv_kernel<<<dim3(BROWS, 7), 256, 0, stream>>>(xbcrawbf, conv_w, conv_b, xbc);
    xt_kernel<<<dim3(128, 25), 256, 0, stream>>>(xbc, xT);

    acs_kernel<<<2 * NH, 256, 0, stream>>>(dtbT, A_log, acs, Tsum);
    states_kernel<<<dim3(NH, NCHUNK, 2), 256, 0, stream>>>(xT, dtbT, acs, Tsum, states);
    scan_kernel<<<dim3(16, NH, 2), 256, 0, stream>>>(Tsum, states);
    yfull_kernel<<<dim3(NH, NCHUNK, 2), 256, 0, stream>>>(xbc, xT, dtbT, acs, states, ybuf);

    norm_kernel<<<BROWS, 256, 0, stream>>>(ybuf, xbc, zbf, Dp, norm_w, ybf);

    // W_out -> bf16 into states region (dead after yfull), then out-projection
    cvt_kernel<<<(DM * DINNER / 4 + 255) / 256, 256, 0, stream>>>(W_out, woutbf, (long)DM * DINNER / 4);
    gemm_bt<0><<<dim3(6, 64), 256, 0, stream>>>(ybf, woutbf, out, DINNER, DM,
                                                nullptr, nullptr, nullptr, nullptr);
}